// Round 1
// baseline (5445.404 us; speedup 1.0000x reference)
//
#include <hip/hip_runtime.h>
#include <cstdint>

typedef unsigned short u16;
typedef __attribute__((ext_vector_type(8))) short s8v;   // 8 x bf16 (4 VGPR)
typedef __attribute__((ext_vector_type(4))) float f4v;   // MFMA 16x16 acc

#define NBLK 256
#define NB0  128
#define TSEQ 200

__device__ __forceinline__ u16 f2bf(float f) {
  uint32_t u = __float_as_uint(f);
  u += 0x7fffu + ((u >> 16) & 1u);
  return (u16)(u >> 16);
}
__device__ __forceinline__ float bf2f(u16 h) {
  return __uint_as_float(((uint32_t)h) << 16);
}
__device__ __forceinline__ float sigf(float x) { return 1.f / (1.f + __expf(-x)); }
__device__ __forceinline__ float tanhfast(float x) { return 2.f / (1.f + __expf(-2.f * x)) - 1.f; }

// ---------------- precompute kernels ----------------

__global__ void zero_ws(uint32_t* p, int n) {
  int i = blockIdx.x * 256 + threadIdx.x;
  if (i < n) p[i] = 0u;
}

// X[t][b(256)][e(128)] bf16, zero-padded rows b>=250 and cols e>=100
__global__ void gather_x(const int* __restrict__ tokens, const float* __restrict__ emb,
                         u16* __restrict__ X) {
  int idx = blockIdx.x * 256 + threadIdx.x;
  if (idx >= TSEQ * 256 * 16) return;
  int e0 = (idx & 15) * 8;
  int b  = (idx >> 4) & 255;
  int t  = idx >> 12;
  u16 v[8];
  if (b < 250) {
    int tok = tokens[b * TSEQ + t];
    const float* er = emb + (size_t)tok * 100;
#pragma unroll
    for (int j = 0; j < 8; ++j) {
      int e = e0 + j;
      v[j] = (e < 100) ? f2bf(er[e]) : (u16)0;
    }
  } else {
#pragma unroll
    for (int j = 0; j < 8; ++j) v[j] = 0;
  }
  *(s8v*)&X[(size_t)idx * 8] = *(const s8v*)v;
}

// out[ub(32)][ks(nks)][col(64)][kw(32)] bf16 ; col = g*16 + j -> orig column g*512 + ub*16 + j
// k = ks*32+kw : k<split -> A (zero for k>=arows), else Bm[k-split]
__global__ void pack_w(const float* __restrict__ A, const float* __restrict__ Bm,
                       u16* __restrict__ out, int nks, int split, int arows) {
  int idx = blockIdx.x * 256 + threadIdx.x;
  int total = 32 * nks * 256;
  if (idx >= total) return;
  int kw0 = (idx & 3) * 8;
  int col = (idx >> 2) & 63;
  int rest = idx >> 8;
  int ks = rest % nks;
  int ub = rest / nks;
  int g = col >> 4, j = col & 15;
  int oc = g * 512 + ub * 16 + j;
  u16 v[8];
#pragma unroll
  for (int w = 0; w < 8; ++w) {
    int k = ks * 32 + kw0 + w;
    float f;
    if (k < split) f = (k < arows) ? A[(size_t)k * 2048 + oc] : 0.f;
    else           f = Bm[(size_t)(k - split) * 2048 + oc];
    v[w] = f2bf(f);
  }
  *(s8v*)&out[(size_t)idx * 8] = *(const s8v*)v;
}

// ---------------- persistent cooperative LSTM kernel ----------------

__device__ __forceinline__ void gbar(unsigned* bar) {
  __syncthreads();
  if (threadIdx.x == 0) {
    __threadfence();  // release
    unsigned old = __hip_atomic_fetch_add(bar, 1u, __ATOMIC_RELAXED, __HIP_MEMORY_SCOPE_AGENT);
    unsigned tgt = (old / NBLK + 1u) * NBLK;
    while (__hip_atomic_load(bar, __ATOMIC_RELAXED, __HIP_MEMORY_SCOPE_AGENT) < tgt)
      __builtin_amdgcn_s_sleep(2);
    __threadfence();  // acquire
  }
  __syncthreads();
}

template <int NK, int SPLIT>
__device__ __forceinline__ void gemm_phase(const u16* __restrict__ A1, const u16* __restrict__ A2,
                                           const u16* __restrict__ lds, int ldsb, f4v acc[4]) {
#pragma unroll
  for (int i = 0; i < NK; ++i) {
    const u16* ap = (i < SPLIT ? A1 : A2) + i * 32;
    s8v a = *(const s8v*)ap;
#pragma unroll
    for (int g = 0; g < 4; ++g) {
      s8v b = *(const s8v*)&lds[i * 2048 + g * 512 + ldsb];
      acc[g] = __builtin_amdgcn_mfma_f32_16x16x32_bf16(a, b, acc[g], 0, 0, 0);
    }
  }
}

__device__ __forceinline__ void epilogue(const f4v acc[4], const float bias[4], float cst[4],
                                         u16* __restrict__ Hout, int drow, int ucol) {
#pragma unroll
  for (int r = 0; r < 4; ++r) {
    float gi = acc[0][r] + bias[0];
    float gf = acc[1][r] + bias[1];
    float gc = acc[2][r] + bias[2];
    float go = acc[3][r] + bias[3];
    float cn = sigf(gf) * cst[r] + sigf(gi) * tanhfast(gc);
    cst[r] = cn;
    Hout[(size_t)(drow + r) * 512 + ucol] = f2bf(sigf(go) * tanhfast(cn));
  }
}

__global__ void __launch_bounds__(256, 1)
lstm_main(const float* __restrict__ b0, const float* __restrict__ b1,
          const u16* __restrict__ W0p, const u16* __restrict__ W1p,
          const u16* __restrict__ X, u16* __restrict__ H0,
          u16* __restrict__ H1, unsigned* __restrict__ bar) {
  extern __shared__ u16 lds[];
  const int tid = threadIdx.x;
  const int lane = tid & 63;
  const int wm = tid >> 6;               // wave id = M sub-tile (16 rows each)
  const int blk = blockIdx.x;
  const bool Lh = (blk >= NB0);          // layer-1 block?
  const int sub = Lh ? blk - NB0 : blk;
  const int ub = sub & 31;               // u-tile (16 units)
  const int mt = sub >> 5;               // M tile (64 rows)
  const int NKr = Lh ? 32 : 20;

  // stationary B slice -> LDS (once). layout [ks][col][kw], identical to pack layout.
  {
    const u16* src = (Lh ? W1p : W0p) + (size_t)ub * (NKr * 2048);
    const int total = NKr * 2048;
    for (int ofs = tid * 8; ofs < total; ofs += 2048)
      *(s8v*)&lds[ofs] = *(const s8v*)&src[ofs];
  }
  __syncthreads();

  const int colu = lane & 15;                        // frag col = u within tile
  const int kch = (lane >> 4) * 8;                   // A/B k-chunk
  const int arow = mt * 64 + wm * 16 + colu;         // A row this lane loads
  const int drow = mt * 64 + wm * 16 + ((lane >> 4) << 2);  // D/C base row
  const int ucol = ub * 16 + colu;                   // global unit index
  const int ldsb = colu * 32 + kch;

  float bias[4];
  {
    const float* bp = Lh ? b1 : b0;
#pragma unroll
    for (int g = 0; g < 4; ++g) bias[g] = bp[g * 512 + ucol];
  }

  float cst[4] = {0.f, 0.f, 0.f, 0.f};
  const size_t HSZ = (size_t)256 * 512;

  for (int p = 0; p <= TSEQ; ++p) {
    const int cur = p & 1;
    const int nxt = cur ^ 1;
    if (!Lh) {
      if (p < TSEQ) {  // layer0 step p: gates = x_p@k0 + h0_{p-1}@r0
        f4v acc[4] = {};
        const u16* A1 = X + ((size_t)p * 256 + arow) * 128 + kch;
        const u16* A2 = H0 + cur * HSZ + (size_t)arow * 512 + kch - 128;
        gemm_phase<20, 4>(A1, A2, lds, ldsb, acc);
        epilogue(acc, bias, cst, H0 + nxt * HSZ, drow, ucol);
      }
    } else {
      if (p >= 1) {  // layer1 step p-1: gates = h0_{p-1}@k1 + h1_{p-2}@r1
        f4v acc[4] = {};
        const u16* A1 = H0 + cur * HSZ + (size_t)arow * 512 + kch;
        const u16* A2 = H1 + cur * HSZ + (size_t)arow * 512 + kch - 512;
        gemm_phase<32, 16>(A1, A2, lds, ldsb, acc);
        epilogue(acc, bias, cst, H1 + nxt * HSZ, drow, ucol);
      }
    }
    gbar(bar);
  }
}

// ---------------- final dense (affine collapse) + sigmoid ----------------

__global__ void dense_out(const u16* __restrict__ H1f, const float* __restrict__ wd1,
                          const float* __restrict__ bd1, const float* __restrict__ wd2,
                          const float* __restrict__ bd2, float* __restrict__ out) {
  __shared__ float wv[512];
  __shared__ float beff;
  const int t = threadIdx.x;  // 512 threads
  {
    float s = 0.f;
#pragma unroll 4
    for (int j = 0; j < 32; ++j) s += wd1[t * 32 + j] * wd2[j];
    wv[t] = s;
  }
  if (t == 0) {
    float sb = 0.f;
    for (int j = 0; j < 32; ++j) sb += bd1[j] * wd2[j];
    beff = sb + bd2[0];
  }
  __syncthreads();
  if (t < 250) {
    const u16* hr = H1f + (size_t)t * 512;
    float acc = 0.f;
    for (int u = 0; u < 512; u += 8) {
      s8v hv = *(const s8v*)&hr[u];
#pragma unroll
      for (int j = 0; j < 8; ++j) acc += bf2f((u16)hv[j]) * wv[u + j];
    }
    out[t] = sigf(acc + beff);
  }
}

// ---------------- host ----------------

extern "C" void kernel_launch(void* const* d_in, const int* in_sizes, int n_in,
                              void* d_out, int out_size, void* d_ws, size_t ws_size,
                              hipStream_t stream) {
  const int*   tokens = (const int*)  d_in[0];
  const float* emb    = (const float*)d_in[1];
  const float* k0     = (const float*)d_in[2];
  const float* r0     = (const float*)d_in[3];
  const float* b0     = (const float*)d_in[4];
  const float* k1     = (const float*)d_in[5];
  const float* r1     = (const float*)d_in[6];
  const float* b1     = (const float*)d_in[7];
  const float* wd1    = (const float*)d_in[8];
  const float* bd1    = (const float*)d_in[9];
  const float* wd2    = (const float*)d_in[10];
  const float* bd2    = (const float*)d_in[11];
  float* out = (float*)d_out;

  char* ws = (char*)d_ws;
  // layout: [0,4096) barrier ; H0 2x256x512 bf16 ; H1 same ; X 200x256x128 bf16 ;
  //         W0p 32x20x64x32 bf16 ; W1p 32x32x64x32 bf16  (total ~20.0 MB)
  unsigned* bar = (unsigned*)ws;
  u16* H0  = (u16*)(ws + 4096);
  u16* H1  = (u16*)(ws + 4096 + 524288);
  u16* X   = (u16*)(ws + 4096 + 2 * 524288);
  u16* W0p = (u16*)(ws + 4096 + 2 * 524288 + 13107200);
  u16* W1p = (u16*)(ws + 4096 + 2 * 524288 + 13107200 + 2621440);

  zero_ws<<<1028, 256, 0, stream>>>((uint32_t*)ws, 263168);          // bar + H0 + H1
  gather_x<<<3200, 256, 0, stream>>>(tokens, emb, X);
  pack_w<<<640,  256, 0, stream>>>(k0, r0, W0p, 20, 128, 100);       // layer0: K=128(pad)+512
  pack_w<<<1024, 256, 0, stream>>>(k1, r1, W1p, 32, 512, 512);       // layer1: K=512+512

  hipFuncSetAttribute(reinterpret_cast<const void*>(lstm_main),
                      hipFuncAttributeMaxDynamicSharedMemorySize, 131072);
  void* args[] = {(void*)&b0, (void*)&b1, (void*)&W0p, (void*)&W1p,
                  (void*)&X,  (void*)&H0, (void*)&H1, (void*)&bar};
  hipLaunchCooperativeKernel(reinterpret_cast<void*>(lstm_main),
                             dim3(NBLK), dim3(256), args, 131072, stream);

  dense_out<<<1, 512, 0, stream>>>(H1 + (size_t)256 * 512, wd1, bd1, wd2, bd2, out);
}

// Round 2
// 3940.008 us; speedup vs baseline: 1.3821x; 1.3821x over previous
//
#include <hip/hip_runtime.h>
#include <cstdint>

typedef unsigned short u16;
typedef __attribute__((ext_vector_type(8))) short s8v;   // 8 x bf16 (4 VGPR)
typedef __attribute__((ext_vector_type(4))) float f4v;   // MFMA 16x16 acc

#define NBLK 128
#define TSEQ 200

__device__ __forceinline__ u16 f2bf(float f) {
  uint32_t u = __float_as_uint(f);
  u += 0x7fffu + ((u >> 16) & 1u);
  return (u16)(u >> 16);
}
__device__ __forceinline__ float bf2f(u16 h) {
  return __uint_as_float(((uint32_t)h) << 16);
}
__device__ __forceinline__ float sigf(float x) { return 1.f / (1.f + __expf(-x)); }
__device__ __forceinline__ float tanhfast(float x) { return 2.f / (1.f + __expf(-2.f * x)) - 1.f; }

// ---------------- precompute kernels ----------------

__global__ void zero_ws(uint32_t* p, int n) {
  int i = blockIdx.x * 256 + threadIdx.x;
  if (i < n) p[i] = 0u;
}

// X[t][b(256)][e(128)] bf16, zero-padded rows b>=250 and cols e>=100
__global__ void gather_x(const int* __restrict__ tokens, const float* __restrict__ emb,
                         u16* __restrict__ X) {
  int idx = blockIdx.x * 256 + threadIdx.x;
  if (idx >= TSEQ * 256 * 16) return;
  int e0 = (idx & 15) * 8;
  int b  = (idx >> 4) & 255;
  int t  = idx >> 12;
  u16 v[8];
  if (b < 250) {
    int tok = tokens[b * TSEQ + t];
    const float* er = emb + (size_t)tok * 100;
#pragma unroll
    for (int j = 0; j < 8; ++j) {
      int e = e0 + j;
      v[j] = (e < 100) ? f2bf(er[e]) : (u16)0;
    }
  } else {
#pragma unroll
    for (int j = 0; j < 8; ++j) v[j] = 0;
  }
  *(s8v*)&X[(size_t)idx * 8] = *(const s8v*)v;
}

// out[ub(32)][ks(nks)][col(64)][kw(32)] bf16 ; col = g*16 + j -> orig column g*512 + ub*16 + j
// k = ks*32+kw : k<split -> A (zero for k>=arows), else Bm[k-split]
__global__ void pack_w(const float* __restrict__ A, const float* __restrict__ Bm,
                       u16* __restrict__ out, int nks, int split, int arows) {
  int idx = blockIdx.x * 256 + threadIdx.x;
  int total = 32 * nks * 256;
  if (idx >= total) return;
  int kw0 = (idx & 3) * 8;
  int col = (idx >> 2) & 63;
  int rest = idx >> 8;
  int ks = rest % nks;
  int ub = rest / nks;
  int g = col >> 4, j = col & 15;
  int oc = g * 512 + ub * 16 + j;
  u16 v[8];
#pragma unroll
  for (int w = 0; w < 8; ++w) {
    int k = ks * 32 + kw0 + w;
    float f;
    if (k < split) f = (k < arows) ? A[(size_t)k * 2048 + oc] : 0.f;
    else           f = Bm[(size_t)(k - split) * 2048 + oc];
    v[w] = f2bf(f);
  }
  *(s8v*)&out[(size_t)idx * 8] = *(const s8v*)v;
}

// ---------------- persistent cooperative LSTM kernel ----------------

// Flag-array barrier: block i stores phase -> flags[i*64]; wave0 lanes poll 2 flags each.
__device__ __forceinline__ void gbar(volatile unsigned* flags, int blk, unsigned tgt) {
  __syncthreads();
  if (threadIdx.x < 64) {
    if (threadIdx.x == 0) {
      __threadfence();  // release: H writes visible before flag
      __hip_atomic_store((unsigned*)&flags[(size_t)blk * 64], tgt,
                         __ATOMIC_RELEASE, __HIP_MEMORY_SCOPE_AGENT);
    }
    const int l = threadIdx.x;
    unsigned a, b;
    do {
      a = __hip_atomic_load((unsigned*)&flags[(size_t)l * 64],
                            __ATOMIC_RELAXED, __HIP_MEMORY_SCOPE_AGENT);
      b = __hip_atomic_load((unsigned*)&flags[(size_t)(l + 64) * 64],
                            __ATOMIC_RELAXED, __HIP_MEMORY_SCOPE_AGENT);
    } while (!__all(a >= tgt && b >= tgt));
    __threadfence();  // acquire
  }
  __syncthreads();
}

// 2 M-tiles per wave: each B-frag read feeds 2 MFMAs (halves LDS traffic).
template <int NK, int SPLIT, int LDA1, int LDA2>
__device__ __forceinline__ void gemm2(const u16* __restrict__ A1, const u16* __restrict__ A2,
                                      const u16* __restrict__ lds, int ldsb, f4v acc[2][4]) {
#pragma unroll
  for (int i = 0; i < NK; ++i) {
    s8v b[4];
#pragma unroll
    for (int g = 0; g < 4; ++g) b[g] = *(const s8v*)&lds[i * 2048 + g * 512 + ldsb];
#pragma unroll
    for (int m = 0; m < 2; ++m) {
      const u16* ap = (i < SPLIT ? A1 + m * 16 * LDA1 : A2 + m * 16 * LDA2) + i * 32;
      s8v a = *(const s8v*)ap;
#pragma unroll
      for (int g = 0; g < 4; ++g)
        acc[m][g] = __builtin_amdgcn_mfma_f32_16x16x32_bf16(a, b[g], acc[m][g], 0, 0, 0);
    }
  }
}

__device__ __forceinline__ void epilogue(const f4v acc[4], const float bias[4], float cst[4],
                                         u16* __restrict__ Hout, int drow, int ucol) {
#pragma unroll
  for (int r = 0; r < 4; ++r) {
    float gi = acc[0][r] + bias[0];
    float gf = acc[1][r] + bias[1];
    float gc = acc[2][r] + bias[2];
    float go = acc[3][r] + bias[3];
    float cn = sigf(gf) * cst[r] + sigf(gi) * tanhfast(gc);
    cst[r] = cn;
    Hout[(size_t)(drow + r) * 512 + ucol] = f2bf(sigf(go) * tanhfast(cn));
  }
}

__global__ void __launch_bounds__(256, 1)
lstm_main(const float* __restrict__ b0, const float* __restrict__ b1,
          const u16* __restrict__ W0p, const u16* __restrict__ W1p,
          const u16* __restrict__ X, u16* __restrict__ H0,
          u16* __restrict__ H1, unsigned* __restrict__ bar) {
  extern __shared__ u16 lds[];
  const int tid = threadIdx.x;
  const int lane = tid & 63;
  const int wm = tid >> 6;               // wave id (0..3)
  const int blk = blockIdx.x;
  const bool Lh = (blk >= 64);           // layer-1 block?
  const int sub = blk & 63;
  const int ub = sub & 31;               // u-tile (16 units)
  const int mt = sub >> 5;               // M half (128 rows)
  const int NKr = Lh ? 32 : 20;

  // stationary B slice -> LDS (once). layout [ks][col][kw].
  {
    const u16* src = (Lh ? W1p : W0p) + (size_t)ub * (NKr * 2048);
    const int total = NKr * 2048;
    for (int ofs = tid * 8; ofs < total; ofs += 2048)
      *(s8v*)&lds[ofs] = *(const s8v*)&src[ofs];
  }
  __syncthreads();

  const int colu = lane & 15;                            // frag col = u within tile
  const int kch = (lane >> 4) * 8;                       // A/B k-chunk
  const int arow0 = mt * 128 + wm * 32 + colu;           // A row, m-tile 0
  const int drow0 = mt * 128 + wm * 32 + ((lane >> 4) << 2);
  const int ucol = ub * 16 + colu;                       // global unit index
  const int ldsb = colu * 32 + kch;

  float bias[4];
  {
    const float* bp = Lh ? b1 : b0;
#pragma unroll
    for (int g = 0; g < 4; ++g) bias[g] = bp[g * 512 + ucol];
  }

  float cst[2][4] = {{0.f, 0.f, 0.f, 0.f}, {0.f, 0.f, 0.f, 0.f}};
  const size_t HSZ = (size_t)256 * 512;

  for (int p = 0; p <= TSEQ; ++p) {
    const int cur = p & 1;
    const int nxt = cur ^ 1;
    if (!Lh) {
      if (p < TSEQ) {  // layer0 step p: gates = x_p@k0 + h0_{p-1}@r0
        f4v acc[2][4] = {};
        const u16* A1 = X + ((size_t)p * 256 + arow0) * 128 + kch;
        const u16* A2 = H0 + cur * HSZ + (size_t)arow0 * 512 + kch - 128;
        gemm2<20, 4, 128, 512>(A1, A2, lds, ldsb, acc);
        epilogue(acc[0], bias, cst[0], H0 + nxt * HSZ, drow0, ucol);
        epilogue(acc[1], bias, cst[1], H0 + nxt * HSZ, drow0 + 16, ucol);
      }
    } else {
      if (p >= 1) {  // layer1 step p-1: gates = h0_{p-1}@k1 + h1_{p-2}@r1
        f4v acc[2][4] = {};
        const u16* A1 = H0 + cur * HSZ + (size_t)arow0 * 512 + kch;
        const u16* A2 = H1 + cur * HSZ + (size_t)arow0 * 512 + kch - 512;
        gemm2<32, 16, 512, 512>(A1, A2, lds, ldsb, acc);
        epilogue(acc[0], bias, cst[0], H1 + nxt * HSZ, drow0, ucol);
        epilogue(acc[1], bias, cst[1], H1 + nxt * HSZ, drow0 + 16, ucol);
      }
    }
    gbar((volatile unsigned*)bar, blk, (unsigned)(p + 1));
  }
}

// ---------------- final dense (affine collapse) + sigmoid ----------------

__global__ void dense_out(const u16* __restrict__ H1f, const float* __restrict__ wd1,
                          const float* __restrict__ bd1, const float* __restrict__ wd2,
                          const float* __restrict__ bd2, float* __restrict__ out) {
  __shared__ float wv[512];
  __shared__ float beff;
  const int t = threadIdx.x;  // 512 threads
  {
    float s = 0.f;
#pragma unroll 4
    for (int j = 0; j < 32; ++j) s += wd1[t * 32 + j] * wd2[j];
    wv[t] = s;
  }
  if (t == 0) {
    float sb = 0.f;
    for (int j = 0; j < 32; ++j) sb += bd1[j] * wd2[j];
    beff = sb + bd2[0];
  }
  __syncthreads();
  if (t < 250) {
    const u16* hr = H1f + (size_t)t * 512;
    float acc = 0.f;
    for (int u = 0; u < 512; u += 8) {
      s8v hv = *(const s8v*)&hr[u];
#pragma unroll
      for (int j = 0; j < 8; ++j) acc += bf2f((u16)hv[j]) * wv[u + j];
    }
    out[t] = sigf(acc + beff);
  }
}

// ---------------- host ----------------

extern "C" void kernel_launch(void* const* d_in, const int* in_sizes, int n_in,
                              void* d_out, int out_size, void* d_ws, size_t ws_size,
                              hipStream_t stream) {
  const int*   tokens = (const int*)  d_in[0];
  const float* emb    = (const float*)d_in[1];
  const float* k0     = (const float*)d_in[2];
  const float* r0     = (const float*)d_in[3];
  const float* b0     = (const float*)d_in[4];
  const float* k1     = (const float*)d_in[5];
  const float* r1     = (const float*)d_in[6];
  const float* b1     = (const float*)d_in[7];
  const float* wd1    = (const float*)d_in[8];
  const float* bd1    = (const float*)d_in[9];
  const float* wd2    = (const float*)d_in[10];
  const float* bd2    = (const float*)d_in[11];
  float* out = (float*)d_out;

  char* ws = (char*)d_ws;
  // layout: [0,32768) flags (128 x 256B) ; H0 2x256x512 bf16 ; H1 same ;
  //         X 200x256x128 bf16 ; W0p 32x20x64x32 bf16 ; W1p 32x32x64x32 bf16
  unsigned* bar = (unsigned*)ws;
  u16* H0  = (u16*)(ws + 32768);
  u16* H1  = (u16*)(ws + 32768 + 524288);
  u16* X   = (u16*)(ws + 32768 + 2 * 524288);
  u16* W0p = (u16*)(ws + 32768 + 2 * 524288 + 13107200);
  u16* W1p = (u16*)(ws + 32768 + 2 * 524288 + 13107200 + 2621440);

  zero_ws<<<1056, 256, 0, stream>>>((uint32_t*)ws, 270336);          // flags + H0 + H1
  gather_x<<<3200, 256, 0, stream>>>(tokens, emb, X);
  pack_w<<<640,  256, 0, stream>>>(k0, r0, W0p, 20, 128, 100);       // layer0: K=128(pad)+512
  pack_w<<<1024, 256, 0, stream>>>(k1, r1, W1p, 32, 512, 512);       // layer1: K=512+512

  hipFuncSetAttribute(reinterpret_cast<const void*>(lstm_main),
                      hipFuncAttributeMaxDynamicSharedMemorySize, 131072);
  void* args[] = {(void*)&b0, (void*)&b1, (void*)&W0p, (void*)&W1p,
                  (void*)&X,  (void*)&H0, (void*)&H1, (void*)&bar};
  hipLaunchCooperativeKernel(reinterpret_cast<void*>(lstm_main),
                             dim3(NBLK), dim3(256), args, 131072, stream);

  dense_out<<<1, 512, 0, stream>>>(H1 + (size_t)256 * 512, wd1, bd1, wd2, bd2, out);
}

// Round 3
// 3795.494 us; speedup vs baseline: 1.4347x; 1.0381x over previous
//
#include <hip/hip_runtime.h>
#include <cstdint>

typedef unsigned short u16;
typedef __attribute__((ext_vector_type(8))) short s8v;   // 8 x bf16 (4 VGPR)
typedef __attribute__((ext_vector_type(4))) float f4v;   // MFMA 16x16 acc

#define NBLK 128
#define TSEQ 200

__device__ __forceinline__ u16 f2bf(float f) {
  uint32_t u = __float_as_uint(f);
  u += 0x7fffu + ((u >> 16) & 1u);
  return (u16)(u >> 16);
}
__device__ __forceinline__ float bf2f(u16 h) {
  return __uint_as_float(((uint32_t)h) << 16);
}
__device__ __forceinline__ float sigf(float x) { return 1.f / (1.f + __expf(-x)); }
__device__ __forceinline__ float tanhfast(float x) { return 2.f / (1.f + __expf(-2.f * x)) - 1.f; }

// ---------------- precompute kernels ----------------

__global__ void zero_ws(uint32_t* p, int n) {
  int i = blockIdx.x * 256 + threadIdx.x;
  if (i < n) p[i] = 0u;
}

// X[t][b(256)][e(128)] bf16, zero-padded rows b>=250 and cols e>=100
__global__ void gather_x(const int* __restrict__ tokens, const float* __restrict__ emb,
                         u16* __restrict__ X) {
  int idx = blockIdx.x * 256 + threadIdx.x;
  if (idx >= TSEQ * 256 * 16) return;
  int e0 = (idx & 15) * 8;
  int b  = (idx >> 4) & 255;
  int t  = idx >> 12;
  u16 v[8];
  if (b < 250) {
    int tok = tokens[b * TSEQ + t];
    const float* er = emb + (size_t)tok * 100;
#pragma unroll
    for (int j = 0; j < 8; ++j) {
      int e = e0 + j;
      v[j] = (e < 100) ? f2bf(er[e]) : (u16)0;
    }
  } else {
#pragma unroll
    for (int j = 0; j < 8; ++j) v[j] = 0;
  }
  *(s8v*)&X[(size_t)idx * 8] = *(const s8v*)v;
}

// out[ub(32)][ks(nks)][col(64)][kw(32)] bf16 with 16B-slot XOR swizzle within each
// 64B kw-row: slot' = slot ^ ((col>>1)&3). col = g*16+j -> orig column g*512+ub*16+j.
// k = ks*32+kw : k<split -> A (zero for k>=arows), else Bm[k-split]
__global__ void pack_w(const float* __restrict__ A, const float* __restrict__ Bm,
                       u16* __restrict__ out, int nks, int split, int arows) {
  int idx = blockIdx.x * 256 + threadIdx.x;
  int total = 32 * nks * 256;
  if (idx >= total) return;
  int kw0 = (idx & 3) * 8;
  int col = (idx >> 2) & 63;
  int rest = idx >> 8;
  int ks = rest % nks;
  int ub = rest / nks;
  int g = col >> 4, j = col & 15;
  int oc = g * 512 + ub * 16 + j;
  u16 v[8];
#pragma unroll
  for (int w = 0; w < 8; ++w) {
    int k = ks * 32 + kw0 + w;
    float f;
    if (k < split) f = (k < arows) ? A[(size_t)k * 2048 + oc] : 0.f;
    else           f = Bm[(size_t)(k - split) * 2048 + oc];
    v[w] = f2bf(f);
  }
  int kw0s = kw0 ^ ((((col >> 1) & 3)) << 3);   // bank-conflict swizzle
  size_t dst = (((size_t)(ub * nks + ks) * 64 + col) * 32) + kw0s;
  *(s8v*)&out[dst] = *(const s8v*)v;
}

// ---------------- persistent cooperative LSTM kernel ----------------

// Flag-array barrier: block i stores phase -> flags[i*64]; wave0 lanes poll 2 flags each.
__device__ __forceinline__ void gbar(volatile unsigned* flags, int blk, unsigned tgt) {
  __syncthreads();
  if (threadIdx.x < 64) {
    if (threadIdx.x == 0) {
      __threadfence();  // release: H writes visible before flag
      __hip_atomic_store((unsigned*)&flags[(size_t)blk * 64], tgt,
                         __ATOMIC_RELEASE, __HIP_MEMORY_SCOPE_AGENT);
    }
    const int l = threadIdx.x;
    unsigned a, b;
    do {
      a = __hip_atomic_load((unsigned*)&flags[(size_t)l * 64],
                            __ATOMIC_RELAXED, __HIP_MEMORY_SCOPE_AGENT);
      b = __hip_atomic_load((unsigned*)&flags[(size_t)(l + 64) * 64],
                            __ATOMIC_RELAXED, __HIP_MEMORY_SCOPE_AGENT);
    } while (!__all(a >= tgt && b >= tgt));
    __threadfence();  // acquire
  }
  __syncthreads();
}

// 2 M-tiles per wave over this wave's K-slice. SPLIT in [0,NK]: i<SPLIT from A1, else A2.
template <int NK, int SPLIT, int LDA1, int LDA2>
__device__ __forceinline__ void gemm2(const u16* __restrict__ A1, const u16* __restrict__ A2,
                                      const u16* __restrict__ ldsW, int ldsb, f4v acc[2][4]) {
#pragma unroll
  for (int i = 0; i < NK; ++i) {
    s8v b[4];
#pragma unroll
    for (int g = 0; g < 4; ++g) b[g] = *(const s8v*)&ldsW[i * 2048 + g * 512 + ldsb];
#pragma unroll
    for (int m = 0; m < 2; ++m) {
      const u16* ap = (i < SPLIT ? A1 + m * 16 * LDA1 : A2 + m * 16 * LDA2) + i * 32;
      s8v a = *(const s8v*)ap;
#pragma unroll
      for (int g = 0; g < 4; ++g)
        acc[m][g] = __builtin_amdgcn_mfma_f32_16x16x32_bf16(a, b[g], acc[m][g], 0, 0, 0);
    }
  }
}

__device__ __forceinline__ void epilogue(const f4v acc[4], const float bias[4], float cst[4],
                                         u16* __restrict__ Hout, int drow, int ucol) {
#pragma unroll
  for (int r = 0; r < 4; ++r) {
    float gi = acc[0][r] + bias[0];
    float gf = acc[1][r] + bias[1];
    float gc = acc[2][r] + bias[2];
    float go = acc[3][r] + bias[3];
    float cn = sigf(gf) * cst[r] + sigf(gi) * tanhfast(gc);
    cst[r] = cn;
    Hout[(size_t)(drow + r) * 512 + ucol] = f2bf(sigf(go) * tanhfast(cn));
  }
}

__global__ void __launch_bounds__(512, 2)
lstm_main(const float* __restrict__ b0, const float* __restrict__ b1,
          const u16* __restrict__ W0p, const u16* __restrict__ W1p,
          const u16* __restrict__ X, u16* __restrict__ H0,
          u16* __restrict__ H1, unsigned* __restrict__ bar) {
  extern __shared__ u16 lds[];
  const int tid = threadIdx.x;
  const int lane = tid & 63;
  const int w = tid >> 6;                // 0..7
  const int wm = w & 3;                  // M sub-position (32 rows each)
  const int kh = w >> 2;                 // K-half (0 or 1)
  const int blk = blockIdx.x;
  const bool Lh = (blk >= 64);           // layer-1 block?
  const int sub = blk & 63;
  const int ub = sub & 31;               // u-tile (16 units)
  const int mt = sub >> 5;               // M half (128 rows)
  const int NKr = Lh ? 32 : 20;

  // stationary B slice -> LDS (once). layout [ks][col][kw], swizzled slots.
  {
    const u16* src = (Lh ? W1p : W0p) + (size_t)ub * (NKr * 2048);
    const int total = NKr * 2048;
    for (int ofs = tid * 8; ofs < total; ofs += 4096)
      *(s8v*)&lds[ofs] = *(const s8v*)&src[ofs];
  }
  __syncthreads();

  const int colu = lane & 15;                            // frag col = u within tile
  const int kch = (lane >> 4) * 8;                       // A/B k-chunk (elements)
  const int kchs = kch ^ ((((colu >> 1) & 3)) << 3);     // swizzled LDS slot
  const int arow0 = mt * 128 + wm * 32 + colu;           // A row, m-tile 0
  const int drow0 = mt * 128 + wm * 32 + ((lane >> 4) << 2);
  const int ucol = ub * 16 + colu;                       // global unit index
  const int ldsb = colu * 32 + kchs;
  float* rbuf = (float*)(lds + 65536);                   // 16 KB reduce buffer @128KB

  float bias[4];
  {
    const float* bp = Lh ? b1 : b0;
#pragma unroll
    for (int g = 0; g < 4; ++g) bias[g] = bp[g * 512 + ucol];
  }

  float cst[2][4] = {{0.f, 0.f, 0.f, 0.f}, {0.f, 0.f, 0.f, 0.f}};
  const size_t HSZ = (size_t)256 * 512;

  for (int p = 0; p <= TSEQ; ++p) {
    const int cur = p & 1;
    const int nxt = cur ^ 1;
    const bool active = Lh ? (p >= 1) : (p < TSEQ);
    f4v acc[2][4] = {};
    if (active) {
      if (!Lh) {
        if (kh == 0) {  // K 0..320: X(128) + H0 cols 0..192
          const u16* A1 = X + ((size_t)p * 256 + arow0) * 128 + kch;
          const u16* A2 = H0 + cur * HSZ + (size_t)arow0 * 512 + kch - 128;
          gemm2<10, 4, 128, 512>(A1, A2, lds, ldsb, acc);
        } else {        // K 320..640: H0 cols 192..512
          const u16* A2 = H0 + cur * HSZ + (size_t)arow0 * 512 + 192 + kch;
          gemm2<10, 0, 512, 512>(A2, A2, lds + 10 * 2048, ldsb, acc);
        }
      } else {
        if (kh == 0) {  // K 0..512: H0 (k1 part)
          const u16* A1 = H0 + cur * HSZ + (size_t)arow0 * 512 + kch;
          gemm2<16, 16, 512, 512>(A1, A1, lds, ldsb, acc);
        } else {        // K 512..1024: H1 (r1 part)
          const u16* A2 = H1 + cur * HSZ + (size_t)arow0 * 512 + kch;
          gemm2<16, 0, 512, 512>(A2, A2, lds + 16 * 2048, ldsb, acc);
        }
      }
    }
    // reduce K-halves: upper waves (kh=1) ship partials to lower via 16KB LDS, 2 rounds.
#pragma unroll
    for (int r = 0; r < 2; ++r) {
      __syncthreads();
      if (kh == 1 && active) {
#pragma unroll
        for (int m = 0; m < 2; ++m)
#pragma unroll
          for (int gg = 0; gg < 2; ++gg) {
            int q = m * 2 + gg;
            *(f4v*)&rbuf[(((size_t)q * 4 + wm) * 64 + lane) * 4] = acc[m][2 * r + gg];
          }
      }
      __syncthreads();
      if (kh == 0 && active) {
#pragma unroll
        for (int m = 0; m < 2; ++m)
#pragma unroll
          for (int gg = 0; gg < 2; ++gg) {
            int q = m * 2 + gg;
            acc[m][2 * r + gg] += *(const f4v*)&rbuf[(((size_t)q * 4 + wm) * 64 + lane) * 4];
          }
      }
    }
    if (active && kh == 0) {
      u16* Hout = (Lh ? H1 : H0) + nxt * HSZ;
      epilogue(acc[0], bias, cst[0], Hout, drow0, ucol);
      epilogue(acc[1], bias, cst[1], Hout, drow0 + 16, ucol);
    }
    gbar((volatile unsigned*)bar, blk, (unsigned)(p + 1));
  }
}

// ---------------- final dense (affine collapse) + sigmoid ----------------

__global__ void dense_out(const u16* __restrict__ H1f, const float* __restrict__ wd1,
                          const float* __restrict__ bd1, const float* __restrict__ wd2,
                          const float* __restrict__ bd2, float* __restrict__ out) {
  __shared__ float wv[512];
  __shared__ float beff;
  const int t = threadIdx.x;  // 512 threads
  {
    float s = 0.f;
#pragma unroll 4
    for (int j = 0; j < 32; ++j) s += wd1[t * 32 + j] * wd2[j];
    wv[t] = s;
  }
  if (t == 0) {
    float sb = 0.f;
    for (int j = 0; j < 32; ++j) sb += bd1[j] * wd2[j];
    beff = sb + bd2[0];
  }
  __syncthreads();
  if (t < 250) {
    const u16* hr = H1f + (size_t)t * 512;
    float acc = 0.f;
    for (int u = 0; u < 512; u += 8) {
      s8v hv = *(const s8v*)&hr[u];
#pragma unroll
      for (int j = 0; j < 8; ++j) acc += bf2f((u16)hv[j]) * wv[u + j];
    }
    out[t] = sigf(acc + beff);
  }
}

// ---------------- host ----------------

extern "C" void kernel_launch(void* const* d_in, const int* in_sizes, int n_in,
                              void* d_out, int out_size, void* d_ws, size_t ws_size,
                              hipStream_t stream) {
  const int*   tokens = (const int*)  d_in[0];
  const float* emb    = (const float*)d_in[1];
  const float* k0     = (const float*)d_in[2];
  const float* r0     = (const float*)d_in[3];
  const float* b0     = (const float*)d_in[4];
  const float* k1     = (const float*)d_in[5];
  const float* r1     = (const float*)d_in[6];
  const float* b1     = (const float*)d_in[7];
  const float* wd1    = (const float*)d_in[8];
  const float* bd1    = (const float*)d_in[9];
  const float* wd2    = (const float*)d_in[10];
  const float* bd2    = (const float*)d_in[11];
  float* out = (float*)d_out;

  char* ws = (char*)d_ws;
  // layout: [0,32768) flags (128 x 256B) ; H0 2x256x512 bf16 ; H1 same ;
  //         X 200x256x128 bf16 ; W0p 32x20x64x32 bf16 ; W1p 32x32x64x32 bf16
  unsigned* bar = (unsigned*)ws;
  u16* H0  = (u16*)(ws + 32768);
  u16* H1  = (u16*)(ws + 32768 + 524288);
  u16* X   = (u16*)(ws + 32768 + 2 * 524288);
  u16* W0p = (u16*)(ws + 32768 + 2 * 524288 + 13107200);
  u16* W1p = (u16*)(ws + 32768 + 2 * 524288 + 13107200 + 2621440);

  zero_ws<<<1056, 256, 0, stream>>>((uint32_t*)ws, 270336);          // flags + H0 + H1
  gather_x<<<3200, 256, 0, stream>>>(tokens, emb, X);
  pack_w<<<640,  256, 0, stream>>>(k0, r0, W0p, 20, 128, 100);       // layer0: K=128(pad)+512
  pack_w<<<1024, 256, 0, stream>>>(k1, r1, W1p, 32, 512, 512);       // layer1: K=512+512

  hipFuncSetAttribute(reinterpret_cast<const void*>(lstm_main),
                      hipFuncAttributeMaxDynamicSharedMemorySize, 147456);
  void* args[] = {(void*)&b0, (void*)&b1, (void*)&W0p, (void*)&W1p,
                  (void*)&X,  (void*)&H0, (void*)&H1, (void*)&bar};
  hipLaunchCooperativeKernel(reinterpret_cast<void*>(lstm_main),
                             dim3(NBLK), dim3(512), args, 147456, stream);

  dense_out<<<1, 512, 0, stream>>>(H1 + (size_t)256 * 512, wd1, bd1, wd2, bd2, out);
}

// Round 4
// 2797.563 us; speedup vs baseline: 1.9465x; 1.3567x over previous
//
#include <hip/hip_runtime.h>
#include <cstdint>

typedef unsigned short u16;
typedef unsigned long long u64;
typedef __attribute__((ext_vector_type(8))) short s8v;   // 8 x bf16 (4 VGPR)
typedef __attribute__((ext_vector_type(4))) float f4v;   // MFMA 16x16 acc

#define NBLK 128
#define TSEQ 200

__device__ __forceinline__ u16 f2bf(float f) {
  uint32_t u = __float_as_uint(f);
  u += 0x7fffu + ((u >> 16) & 1u);
  return (u16)(u >> 16);
}
__device__ __forceinline__ float bf2f(u16 h) {
  return __uint_as_float(((uint32_t)h) << 16);
}
__device__ __forceinline__ float sigf(float x) { return 1.f / (1.f + __expf(-x)); }
__device__ __forceinline__ float tanhfast(float x) { return 2.f / (1.f + __expf(-2.f * x)) - 1.f; }

// coherent (LLC-level) 16B load / 2B store — bypass non-coherent per-XCD L2
__device__ __forceinline__ void cload(s8v& d, const u16* p) {
  asm volatile("global_load_dwordx4 %0, %1, off sc0 sc1" : "=v"(d) : "v"(p));
}
__device__ __forceinline__ void cstore(u16* p, u16 v) {
  asm volatile("global_store_short %0, %1, off sc0 sc1" :: "v"(p), "v"((uint32_t)v) : "memory");
}

// ---------------- precompute kernels ----------------

__global__ void zero_ws(uint32_t* p, int n) {
  int i = blockIdx.x * 256 + threadIdx.x;
  if (i < n) p[i] = 0u;
}

// X[t][b(256)][e(128)] bf16, zero-padded rows b>=250 and cols e>=100
__global__ void gather_x(const int* __restrict__ tokens, const float* __restrict__ emb,
                         u16* __restrict__ X) {
  int idx = blockIdx.x * 256 + threadIdx.x;
  if (idx >= TSEQ * 256 * 16) return;
  int e0 = (idx & 15) * 8;
  int b  = (idx >> 4) & 255;
  int t  = idx >> 12;
  u16 v[8];
  if (b < 250) {
    int tok = tokens[b * TSEQ + t];
    const float* er = emb + (size_t)tok * 100;
#pragma unroll
    for (int j = 0; j < 8; ++j) {
      int e = e0 + j;
      v[j] = (e < 100) ? f2bf(er[e]) : (u16)0;
    }
  } else {
#pragma unroll
    for (int j = 0; j < 8; ++j) v[j] = 0;
  }
  *(s8v*)&X[(size_t)idx * 8] = *(const s8v*)v;
}

// out[ub(32)][ks(nks)][col(64)][kw(32)] bf16 with 16B-slot XOR swizzle within each
// 64B kw-row: slot' = slot ^ ((col>>1)&3). col = g*16+j -> orig column g*512+ub*16+j.
// k = ks*32+kw : k<split -> A (zero for k>=arows), else Bm[k-split]
__global__ void pack_w(const float* __restrict__ A, const float* __restrict__ Bm,
                       u16* __restrict__ out, int nks, int split, int arows) {
  int idx = blockIdx.x * 256 + threadIdx.x;
  int total = 32 * nks * 256;
  if (idx >= total) return;
  int kw0 = (idx & 3) * 8;
  int col = (idx >> 2) & 63;
  int rest = idx >> 8;
  int ks = rest % nks;
  int ub = rest / nks;
  int g = col >> 4, j = col & 15;
  int oc = g * 512 + ub * 16 + j;
  u16 v[8];
#pragma unroll
  for (int w = 0; w < 8; ++w) {
    int k = ks * 32 + kw0 + w;
    float f;
    if (k < split) f = (k < arows) ? A[(size_t)k * 2048 + oc] : 0.f;
    else           f = Bm[(size_t)(k - split) * 2048 + oc];
    v[w] = f2bf(f);
  }
  int kw0s = kw0 ^ ((((col >> 1) & 3)) << 3);   // bank-conflict swizzle
  size_t dst = (((size_t)(ub * nks + ks) * 64 + col) * 32) + kw0s;
  *(s8v*)&out[dst] = *(const s8v*)v;
}

// ---------------- persistent cooperative LSTM kernel ----------------

// Fence-free barrier: sc1 stores drained per-wave, flag store + 8B-load poll, no cache ops.
__device__ __forceinline__ void gbar(unsigned* flags, int blk, unsigned tgt) {
  asm volatile("s_waitcnt vmcnt(0)" ::: "memory");   // my sc1 H-stores are at LLC
  __syncthreads();                                   // all waves drained
  if (threadIdx.x < 64) {
    if (threadIdx.x == 0)
      __hip_atomic_store(&flags[blk], tgt, __ATOMIC_RELAXED, __HIP_MEMORY_SCOPE_AGENT);
    const int l = threadIdx.x;
    u64 v;
    do {
      v = __hip_atomic_load((u64*)&flags[2 * l], __ATOMIC_RELAXED, __HIP_MEMORY_SCOPE_AGENT);
    } while (!__all(((unsigned)v >= tgt) && ((unsigned)(v >> 32) >= tgt)));
  }
  asm volatile("" ::: "memory");                     // compiler barrier (no HW op)
  __syncthreads();
}

// One K-segment: batch-load the A-panel (2 m-tiles x NK steps) into regs, then MFMA.
// COH: coherent sc1 asm loads (H state). !COH: plain cached loads (static X).
template <int NK, bool COH>
__device__ __forceinline__ void gemmseg(const u16* __restrict__ A, int lda,
                                        const u16* __restrict__ ldsW, int ldsb,
                                        f4v acc[2][4]) {
  s8v a[2][NK];
  if (COH) {
#pragma unroll
    for (int i = 0; i < NK; ++i) {
      cload(a[0][i], A + i * 32);
      cload(a[1][i], A + 16 * lda + i * 32);
    }
    asm volatile("s_waitcnt vmcnt(0)" ::: "memory");
    __builtin_amdgcn_sched_barrier(0);
  } else {
#pragma unroll
    for (int i = 0; i < NK; ++i) {
      a[0][i] = *(const s8v*)(A + i * 32);
      a[1][i] = *(const s8v*)(A + 16 * lda + i * 32);
    }
  }
#pragma unroll
  for (int i = 0; i < NK; ++i) {
    s8v b[4];
#pragma unroll
    for (int g = 0; g < 4; ++g) b[g] = *(const s8v*)&ldsW[i * 2048 + g * 512 + ldsb];
#pragma unroll
    for (int m = 0; m < 2; ++m)
#pragma unroll
      for (int g = 0; g < 4; ++g)
        acc[m][g] = __builtin_amdgcn_mfma_f32_16x16x32_bf16(a[m][i], b[g], acc[m][g], 0, 0, 0);
  }
}

__device__ __forceinline__ void epilogue(const f4v acc[4], const float bias[4], float cst[4],
                                         u16* __restrict__ Hout, int drow, int ucol) {
#pragma unroll
  for (int r = 0; r < 4; ++r) {
    float gi = acc[0][r] + bias[0];
    float gf = acc[1][r] + bias[1];
    float gc = acc[2][r] + bias[2];
    float go = acc[3][r] + bias[3];
    float cn = sigf(gf) * cst[r] + sigf(gi) * tanhfast(gc);
    cst[r] = cn;
    cstore(&Hout[(size_t)(drow + r) * 512 + ucol], f2bf(sigf(go) * tanhfast(cn)));
  }
}

__global__ void __launch_bounds__(512, 2)
lstm_main(const float* __restrict__ b0, const float* __restrict__ b1,
          const u16* __restrict__ W0p, const u16* __restrict__ W1p,
          const u16* __restrict__ X, u16* __restrict__ H0,
          u16* __restrict__ H1, unsigned* __restrict__ bar) {
  extern __shared__ u16 lds[];
  const int tid = threadIdx.x;
  const int lane = tid & 63;
  const int w = tid >> 6;                // 0..7
  const int wm = w & 3;                  // M sub-position (32 rows each)
  const int kh = w >> 2;                 // K-half (0 or 1)
  const int blk = blockIdx.x;
  const bool Lh = (blk >= 64);           // layer-1 block?
  const int sub = blk & 63;
  const int ub = sub & 31;               // u-tile (16 units)
  const int mt = sub >> 5;               // M half (128 rows)
  const int NKr = Lh ? 32 : 20;

  // stationary B slice -> LDS (once). layout [ks][col][kw], swizzled slots.
  {
    const u16* src = (Lh ? W1p : W0p) + (size_t)ub * (NKr * 2048);
    const int total = NKr * 2048;
    for (int ofs = tid * 8; ofs < total; ofs += 4096)
      *(s8v*)&lds[ofs] = *(const s8v*)&src[ofs];
  }
  __syncthreads();

  const int colu = lane & 15;                            // frag col = u within tile
  const int kch = (lane >> 4) * 8;                       // A/B k-chunk (elements)
  const int kchs = kch ^ ((((colu >> 1) & 3)) << 3);     // swizzled LDS slot
  const int arow0 = mt * 128 + wm * 32 + colu;           // A row, m-tile 0
  const int drow0 = mt * 128 + wm * 32 + ((lane >> 4) << 2);
  const int ucol = ub * 16 + colu;                       // global unit index
  const int ldsb = colu * 32 + kchs;
  float* rbuf = (float*)(lds + 65536);                   // 16 KB reduce buffer @128KB

  float bias[4];
  {
    const float* bp = Lh ? b1 : b0;
#pragma unroll
    for (int g = 0; g < 4; ++g) bias[g] = bp[g * 512 + ucol];
  }

  float cst[2][4] = {{0.f, 0.f, 0.f, 0.f}, {0.f, 0.f, 0.f, 0.f}};
  const size_t HSZ = (size_t)256 * 512;

  for (int p = 0; p <= TSEQ; ++p) {
    const int cur = p & 1;
    const int nxt = cur ^ 1;
    const bool active = Lh ? (p >= 1) : (p < TSEQ);
    f4v acc[2][4] = {};
    if (active) {
      if (!Lh) {
        if (kh == 0) {  // K 0..320: X(128 cols, 4 steps) + H0 cols 0..192 (6 steps)
          gemmseg<4, false>(X + ((size_t)p * 256 + arow0) * 128 + kch, 128,
                            lds, ldsb, acc);
          gemmseg<6, true>(H0 + cur * HSZ + (size_t)arow0 * 512 + kch, 512,
                           lds + 4 * 2048, ldsb, acc);
        } else {        // K 320..640: H0 cols 192..512 (10 steps)
          gemmseg<10, true>(H0 + cur * HSZ + (size_t)arow0 * 512 + 192 + kch, 512,
                            lds + 10 * 2048, ldsb, acc);
        }
      } else {
        if (kh == 0) {  // K 0..512: H0 (k1 part)
          gemmseg<16, true>(H0 + cur * HSZ + (size_t)arow0 * 512 + kch, 512,
                            lds, ldsb, acc);
        } else {        // K 512..1024: H1 (r1 part)
          gemmseg<16, true>(H1 + cur * HSZ + (size_t)arow0 * 512 + kch, 512,
                            lds + 16 * 2048, ldsb, acc);
        }
      }
    }
    // reduce K-halves: upper waves (kh=1) ship partials to lower via 16KB LDS, 2 rounds.
#pragma unroll
    for (int r = 0; r < 2; ++r) {
      __syncthreads();
      if (kh == 1 && active) {
#pragma unroll
        for (int m = 0; m < 2; ++m)
#pragma unroll
          for (int gg = 0; gg < 2; ++gg) {
            int q = m * 2 + gg;
            *(f4v*)&rbuf[(((size_t)q * 4 + wm) * 64 + lane) * 4] = acc[m][2 * r + gg];
          }
      }
      __syncthreads();
      if (kh == 0 && active) {
#pragma unroll
        for (int m = 0; m < 2; ++m)
#pragma unroll
          for (int gg = 0; gg < 2; ++gg) {
            int q = m * 2 + gg;
            acc[m][2 * r + gg] += *(const f4v*)&rbuf[(((size_t)q * 4 + wm) * 64 + lane) * 4];
          }
      }
    }
    if (active && kh == 0) {
      u16* Hout = (Lh ? H1 : H0) + nxt * HSZ;
      epilogue(acc[0], bias, cst[0], Hout, drow0, ucol);
      epilogue(acc[1], bias, cst[1], Hout, drow0 + 16, ucol);
    }
    gbar(bar, blk, (unsigned)(p + 1));
  }
}

// ---------------- final dense (affine collapse) + sigmoid ----------------

__global__ void dense_out(const u16* __restrict__ H1f, const float* __restrict__ wd1,
                          const float* __restrict__ bd1, const float* __restrict__ wd2,
                          const float* __restrict__ bd2, float* __restrict__ out) {
  __shared__ float wv[512];
  __shared__ float beff;
  const int t = threadIdx.x;  // 512 threads
  {
    float s = 0.f;
#pragma unroll 4
    for (int j = 0; j < 32; ++j) s += wd1[t * 32 + j] * wd2[j];
    wv[t] = s;
  }
  if (t == 0) {
    float sb = 0.f;
    for (int j = 0; j < 32; ++j) sb += bd1[j] * wd2[j];
    beff = sb + bd2[0];
  }
  __syncthreads();
  if (t < 250) {
    const u16* hr = H1f + (size_t)t * 512;
    float acc = 0.f;
    for (int u = 0; u < 512; u += 8) {
      s8v hv = *(const s8v*)&hr[u];
#pragma unroll
      for (int j = 0; j < 8; ++j) acc += bf2f((u16)hv[j]) * wv[u + j];
    }
    out[t] = sigf(acc + beff);
  }
}

// ---------------- host ----------------

extern "C" void kernel_launch(void* const* d_in, const int* in_sizes, int n_in,
                              void* d_out, int out_size, void* d_ws, size_t ws_size,
                              hipStream_t stream) {
  const int*   tokens = (const int*)  d_in[0];
  const float* emb    = (const float*)d_in[1];
  const float* k0     = (const float*)d_in[2];
  const float* r0     = (const float*)d_in[3];
  const float* b0     = (const float*)d_in[4];
  const float* k1     = (const float*)d_in[5];
  const float* r1     = (const float*)d_in[6];
  const float* b1     = (const float*)d_in[7];
  const float* wd1    = (const float*)d_in[8];
  const float* bd1    = (const float*)d_in[9];
  const float* wd2    = (const float*)d_in[10];
  const float* bd2    = (const float*)d_in[11];
  float* out = (float*)d_out;

  char* ws = (char*)d_ws;
  // layout: [0,4096) flags (128 x u32, compact) ; H0 2x256x512 bf16 ; H1 same ;
  //         X 200x256x128 bf16 ; W0p 32x20x64x32 bf16 ; W1p 32x32x64x32 bf16
  unsigned* bar = (unsigned*)ws;
  u16* H0  = (u16*)(ws + 4096);
  u16* H1  = (u16*)(ws + 4096 + 524288);
  u16* X   = (u16*)(ws + 4096 + 2 * 524288);
  u16* W0p = (u16*)(ws + 4096 + 2 * 524288 + 13107200);
  u16* W1p = (u16*)(ws + 4096 + 2 * 524288 + 13107200 + 2621440);

  zero_ws<<<1028, 256, 0, stream>>>((uint32_t*)ws, 263168);          // flags + H0 + H1
  gather_x<<<3200, 256, 0, stream>>>(tokens, emb, X);
  pack_w<<<640,  256, 0, stream>>>(k0, r0, W0p, 20, 128, 100);       // layer0: K=128(pad)+512
  pack_w<<<1024, 256, 0, stream>>>(k1, r1, W1p, 32, 512, 512);       // layer1: K=512+512

  hipFuncSetAttribute(reinterpret_cast<const void*>(lstm_main),
                      hipFuncAttributeMaxDynamicSharedMemorySize, 147456);
  void* args[] = {(void*)&b0, (void*)&b1, (void*)&W0p, (void*)&W1p,
                  (void*)&X,  (void*)&H0, (void*)&H1, (void*)&bar};
  hipLaunchCooperativeKernel(reinterpret_cast<void*>(lstm_main),
                             dim3(NBLK), dim3(512), args, 147456, stream);

  dense_out<<<1, 512, 0, stream>>>(H1 + (size_t)256 * 512, wd1, bd1, wd2, bd2, out);
}

// Round 6
// 2578.398 us; speedup vs baseline: 2.1119x; 1.0850x over previous
//
#include <hip/hip_runtime.h>
#include <cstdint>

typedef unsigned short u16;
typedef unsigned long long u64;
typedef __attribute__((ext_vector_type(8))) short s8v;   // 8 x bf16 (4 VGPR)
typedef __attribute__((ext_vector_type(4))) float f4v;   // MFMA 16x16 acc

#define NBLK 128
#define TSEQ 200
#define PIPE_W 8

__device__ __forceinline__ u16 f2bf(float f) {
  uint32_t u = __float_as_uint(f);
  u += 0x7fffu + ((u >> 16) & 1u);
  return (u16)(u >> 16);
}
__device__ __forceinline__ float bf2f(u16 h) {
  return __uint_as_float(((uint32_t)h) << 16);
}
__device__ __forceinline__ float sigf(float x) { return 1.f / (1.f + __expf(-x)); }
__device__ __forceinline__ float tanhfast(float x) { return 2.f / (1.f + __expf(-2.f * x)) - 1.f; }

// asm loads so ALL vmem in the phase is under counted-vmcnt control.
// ld_c: coherent (LLC) for H state; ld_nc: plain cached for static X.
// NOTE: offset: must precede sc0/sc1 on gfx950.
__device__ __forceinline__ void ld_c(s8v& d, const u16* p, int ofs) {
  asm volatile("global_load_dwordx4 %0, %1, off offset:%2 sc0 sc1"
               : "=v"(d) : "v"(p), "n"(ofs));
}
__device__ __forceinline__ void ld_nc(s8v& d, const u16* p, int ofs) {
  asm volatile("global_load_dwordx4 %0, %1, off offset:%2"
               : "=v"(d) : "v"(p), "n"(ofs));
}
__device__ __forceinline__ void vmwait(int n) {
  asm volatile("s_waitcnt vmcnt(%0)" :: "n"(n) : "memory");
}
__device__ __forceinline__ void cstore(u16* p, u16 v) {
  asm volatile("global_store_short %0, %1, off sc0 sc1" :: "v"(p), "v"((uint32_t)v) : "memory");
}

// ---------------- precompute kernels ----------------

__global__ void zero_ws(uint32_t* p, int n) {
  int i = blockIdx.x * 256 + threadIdx.x;
  if (i < n) p[i] = 0u;
}

// X[t][b(256)][e(128)] bf16, zero-padded rows b>=250 and cols e>=100
__global__ void gather_x(const int* __restrict__ tokens, const float* __restrict__ emb,
                         u16* __restrict__ X) {
  int idx = blockIdx.x * 256 + threadIdx.x;
  if (idx >= TSEQ * 256 * 16) return;
  int e0 = (idx & 15) * 8;
  int b  = (idx >> 4) & 255;
  int t  = idx >> 12;
  u16 v[8];
  if (b < 250) {
    int tok = tokens[b * TSEQ + t];
    const float* er = emb + (size_t)tok * 100;
#pragma unroll
    for (int j = 0; j < 8; ++j) {
      int e = e0 + j;
      v[j] = (e < 100) ? f2bf(er[e]) : (u16)0;
    }
  } else {
#pragma unroll
    for (int j = 0; j < 8; ++j) v[j] = 0;
  }
  *(s8v*)&X[(size_t)idx * 8] = *(const s8v*)v;
}

// out[ub(32)][ks(nks)][col(64)][kw(32)] bf16 with 16B-slot XOR swizzle within each
// 64B kw-row: slot' = slot ^ ((col>>1)&3). col = g*16+j -> orig column g*512+ub*16+j.
// k = ks*32+kw : k<split -> A (zero for k>=arows), else Bm[k-split]
__global__ void pack_w(const float* __restrict__ A, const float* __restrict__ Bm,
                       u16* __restrict__ out, int nks, int split, int arows) {
  int idx = blockIdx.x * 256 + threadIdx.x;
  int total = 32 * nks * 256;
  if (idx >= total) return;
  int kw0 = (idx & 3) * 8;
  int col = (idx >> 2) & 63;
  int rest = idx >> 8;
  int ks = rest % nks;
  int ub = rest / nks;
  int g = col >> 4, j = col & 15;
  int oc = g * 512 + ub * 16 + j;
  u16 v[8];
#pragma unroll
  for (int w = 0; w < 8; ++w) {
    int k = ks * 32 + kw0 + w;
    float f;
    if (k < split) f = (k < arows) ? A[(size_t)k * 2048 + oc] : 0.f;
    else           f = Bm[(size_t)(k - split) * 2048 + oc];
    v[w] = f2bf(f);
  }
  int kw0s = kw0 ^ ((((col >> 1) & 3)) << 3);   // bank-conflict swizzle
  size_t dst = (((size_t)(ub * nks + ks) * 64 + col) * 32) + kw0s;
  *(s8v*)&out[dst] = *(const s8v*)v;
}

// ---------------- persistent cooperative LSTM kernel ----------------

// Fence-free barrier: sc1 stores drained per-wave, flag store + 8B-load poll, no cache ops.
__device__ __forceinline__ void gbar(unsigned* flags, int blk, unsigned tgt) {
  asm volatile("s_waitcnt vmcnt(0)" ::: "memory");   // my sc1 H-stores are at LLC
  __syncthreads();                                   // all waves drained
  if (threadIdx.x < 64) {
    if (threadIdx.x == 0)
      __hip_atomic_store(&flags[blk], tgt, __ATOMIC_RELAXED, __HIP_MEMORY_SCOPE_AGENT);
    const int l = threadIdx.x;
    u64 v;
    do {
      v = __hip_atomic_load((u64*)&flags[2 * l], __ATOMIC_RELAXED, __HIP_MEMORY_SCOPE_AGENT);
    } while (!__all(((unsigned)v >= tgt) && ((unsigned)(v >> 32) >= tgt)));
  }
  asm volatile("" ::: "memory");                     // compiler barrier (no HW op)
  __syncthreads();
}

// Windowed software pipeline over NK k-steps, 2 m-tiles. Steps i<NX load from X
// (plain), others from H (sc1 coherent). Counted vmcnt keeps W steps in flight;
// never drains mid-segment. Offsets are compile-time immediates.
template <int NK, int NX>
__device__ __forceinline__ void gemmpipe(const u16* ax0, const u16* ax1,
                                         const u16* ah0, const u16* ah1,
                                         const u16* ldsW, int ldsb, f4v acc[2][4]) {
  s8v a[2][NK];
  constexpr int W = (PIPE_W < NK) ? PIPE_W : NK;
#pragma unroll
  for (int i = 0; i < W; ++i) {
    if (i < NX) { ld_nc(a[0][i], ax0, i * 64); ld_nc(a[1][i], ax1, i * 64); }
    else        { ld_c(a[0][i], ah0, (i - NX) * 64); ld_c(a[1][i], ah1, (i - NX) * 64); }
  }
#pragma unroll
  for (int i = 0; i < NK; ++i) {
    if (i + W < NK) {
      const int j = i + W;
      if (j < NX) { ld_nc(a[0][j], ax0, j * 64); ld_nc(a[1][j], ax1, j * 64); }
      else        { ld_c(a[0][j], ah0, (j - NX) * 64); ld_c(a[1][j], ah1, (j - NX) * 64); }
    }
    const int rem = NK - 1 - i;
    vmwait(2 * (W < rem ? W : rem));   // step i's 2 loads complete; window stays full
    __builtin_amdgcn_sched_barrier(0); // don't hoist MFMA above the wait (rule 18)
    s8v b[4];
#pragma unroll
    for (int g = 0; g < 4; ++g) b[g] = *(const s8v*)&ldsW[i * 2048 + g * 512 + ldsb];
#pragma unroll
    for (int m = 0; m < 2; ++m)
#pragma unroll
      for (int g = 0; g < 4; ++g)
        acc[m][g] = __builtin_amdgcn_mfma_f32_16x16x32_bf16(a[m][i], b[g], acc[m][g], 0, 0, 0);
  }
}

__device__ __forceinline__ void epilogue(const f4v acc[4], const float bias[4], float cst[4],
                                         u16* __restrict__ Hout, int drow, int ucol) {
#pragma unroll
  for (int r = 0; r < 4; ++r) {
    float gi = acc[0][r] + bias[0];
    float gf = acc[1][r] + bias[1];
    float gc = acc[2][r] + bias[2];
    float go = acc[3][r] + bias[3];
    float cn = sigf(gf) * cst[r] + sigf(gi) * tanhfast(gc);
    cst[r] = cn;
    cstore(&Hout[(size_t)(drow + r) * 512 + ucol], f2bf(sigf(go) * tanhfast(cn)));
  }
}

__global__ void __launch_bounds__(512, 2)
lstm_main(const float* __restrict__ b0, const float* __restrict__ b1,
          const u16* __restrict__ W0p, const u16* __restrict__ W1p,
          const u16* __restrict__ X, u16* __restrict__ H0,
          u16* __restrict__ H1, unsigned* __restrict__ bar) {
  extern __shared__ u16 lds[];
  const int tid = threadIdx.x;
  const int lane = tid & 63;
  const int w = tid >> 6;                // 0..7
  const int wm = w & 3;                  // M sub-position (32 rows each)
  const int kh = w >> 2;                 // K-half (0 or 1)
  const int blk = blockIdx.x;
  const bool Lh = (blk >= 64);           // layer-1 block?
  const int sub = blk & 63;
  const int ub = sub & 31;               // u-tile (16 units)
  const int mt = sub >> 5;               // M half (128 rows)
  const int NKr = Lh ? 32 : 20;

  // stationary B slice -> LDS (once). layout [ks][col][kw], swizzled slots.
  {
    const u16* src = (Lh ? W1p : W0p) + (size_t)ub * (NKr * 2048);
    const int total = NKr * 2048;
    for (int ofs = tid * 8; ofs < total; ofs += 4096)
      *(s8v*)&lds[ofs] = *(const s8v*)&src[ofs];
  }
  __syncthreads();

  const int colu = lane & 15;                            // frag col = u within tile
  const int kch = (lane >> 4) * 8;                       // A/B k-chunk (elements)
  const int kchs = kch ^ ((((colu >> 1) & 3)) << 3);     // swizzled LDS slot
  const int arow0 = mt * 128 + wm * 32 + colu;           // A row, m-tile 0
  const int drow0 = mt * 128 + wm * 32 + ((lane >> 4) << 2);
  const int ucol = ub * 16 + colu;                       // global unit index
  const int ldsb = colu * 32 + kchs;
  float* rbuf = (float*)(lds + 65536);                   // 16 KB reduce buffer @128KB

  float bias[4];
  {
    const float* bp = Lh ? b1 : b0;
#pragma unroll
    for (int g = 0; g < 4; ++g) bias[g] = bp[g * 512 + ucol];
  }

  float cst[2][4] = {{0.f, 0.f, 0.f, 0.f}, {0.f, 0.f, 0.f, 0.f}};
  const size_t HSZ = (size_t)256 * 512;

  for (int p = 0; p <= TSEQ; ++p) {
    const int cur = p & 1;
    const int nxt = cur ^ 1;
    const bool active = Lh ? (p >= 1) : (p < TSEQ);
    f4v acc[2][4] = {};
    if (active) {
      if (!Lh) {
        if (kh == 0) {  // K 0..320: X (4 steps, plain) + H0 cols 0..192 (6 steps, sc1)
          const u16* ax0 = X + ((size_t)p * 256 + arow0) * 128 + kch;
          const u16* ah0 = H0 + cur * HSZ + (size_t)arow0 * 512 + kch;
          gemmpipe<10, 4>(ax0, ax0 + 16 * 128, ah0, ah0 + 16 * 512, lds, ldsb, acc);
        } else {        // K 320..640: H0 cols 192..512 (10 steps)
          const u16* ah0 = H0 + cur * HSZ + (size_t)arow0 * 512 + 192 + kch;
          gemmpipe<10, 0>(ah0, ah0, ah0, ah0 + 16 * 512, lds + 10 * 2048, ldsb, acc);
        }
      } else {
        if (kh == 0) {  // K 0..512: H0 (k1 part)
          const u16* ah0 = H0 + cur * HSZ + (size_t)arow0 * 512 + kch;
          gemmpipe<16, 0>(ah0, ah0, ah0, ah0 + 16 * 512, lds, ldsb, acc);
        } else {        // K 512..1024: H1 (r1 part)
          const u16* ah0 = H1 + cur * HSZ + (size_t)arow0 * 512 + kch;
          gemmpipe<16, 0>(ah0, ah0, ah0, ah0 + 16 * 512, lds + 16 * 2048, ldsb, acc);
        }
      }
    }
    // reduce K-halves: upper waves (kh=1) ship partials to lower via 16KB LDS, 2 rounds.
#pragma unroll
    for (int r = 0; r < 2; ++r) {
      __syncthreads();
      if (kh == 1 && active) {
#pragma unroll
        for (int m = 0; m < 2; ++m)
#pragma unroll
          for (int gg = 0; gg < 2; ++gg) {
            int q = m * 2 + gg;
            *(f4v*)&rbuf[(((size_t)q * 4 + wm) * 64 + lane) * 4] = acc[m][2 * r + gg];
          }
      }
      __syncthreads();
      if (kh == 0 && active) {
#pragma unroll
        for (int m = 0; m < 2; ++m)
#pragma unroll
          for (int gg = 0; gg < 2; ++gg) {
            int q = m * 2 + gg;
            acc[m][2 * r + gg] += *(const f4v*)&rbuf[(((size_t)q * 4 + wm) * 64 + lane) * 4];
          }
      }
    }
    if (active && kh == 0) {
      u16* Hout = (Lh ? H1 : H0) + nxt * HSZ;
      epilogue(acc[0], bias, cst[0], Hout, drow0, ucol);
      epilogue(acc[1], bias, cst[1], Hout, drow0 + 16, ucol);
    }
    gbar(bar, blk, (unsigned)(p + 1));
  }
}

// ---------------- final dense (affine collapse) + sigmoid ----------------

__global__ void dense_out(const u16* __restrict__ H1f, const float* __restrict__ wd1,
                          const float* __restrict__ bd1, const float* __restrict__ wd2,
                          const float* __restrict__ bd2, float* __restrict__ out) {
  __shared__ float wv[512];
  __shared__ float beff;
  const int t = threadIdx.x;  // 512 threads
  {
    float s = 0.f;
#pragma unroll 4
    for (int j = 0; j < 32; ++j) s += wd1[t * 32 + j] * wd2[j];
    wv[t] = s;
  }
  if (t == 0) {
    float sb = 0.f;
    for (int j = 0; j < 32; ++j) sb += bd1[j] * wd2[j];
    beff = sb + bd2[0];
  }
  __syncthreads();
  if (t < 250) {
    const u16* hr = H1f + (size_t)t * 512;
    float acc = 0.f;
    for (int u = 0; u < 512; u += 8) {
      s8v hv = *(const s8v*)&hr[u];
#pragma unroll
      for (int j = 0; j < 8; ++j) acc += bf2f((u16)hv[j]) * wv[u + j];
    }
    out[t] = sigf(acc + beff);
  }
}

// ---------------- host ----------------

extern "C" void kernel_launch(void* const* d_in, const int* in_sizes, int n_in,
                              void* d_out, int out_size, void* d_ws, size_t ws_size,
                              hipStream_t stream) {
  const int*   tokens = (const int*)  d_in[0];
  const float* emb    = (const float*)d_in[1];
  const float* k0     = (const float*)d_in[2];
  const float* r0     = (const float*)d_in[3];
  const float* b0     = (const float*)d_in[4];
  const float* k1     = (const float*)d_in[5];
  const float* r1     = (const float*)d_in[6];
  const float* b1     = (const float*)d_in[7];
  const float* wd1    = (const float*)d_in[8];
  const float* bd1    = (const float*)d_in[9];
  const float* wd2    = (const float*)d_in[10];
  const float* bd2    = (const float*)d_in[11];
  float* out = (float*)d_out;

  char* ws = (char*)d_ws;
  // layout: [0,4096) flags (128 x u32, compact) ; H0 2x256x512 bf16 ; H1 same ;
  //         X 200x256x128 bf16 ; W0p 32x20x64x32 bf16 ; W1p 32x32x64x32 bf16
  unsigned* bar = (unsigned*)ws;
  u16* H0  = (u16*)(ws + 4096);
  u16* H1  = (u16*)(ws + 4096 + 524288);
  u16* X   = (u16*)(ws + 4096 + 2 * 524288);
  u16* W0p = (u16*)(ws + 4096 + 2 * 524288 + 13107200);
  u16* W1p = (u16*)(ws + 4096 + 2 * 524288 + 13107200 + 2621440);

  zero_ws<<<1028, 256, 0, stream>>>((uint32_t*)ws, 263168);          // flags + H0 + H1
  gather_x<<<3200, 256, 0, stream>>>(tokens, emb, X);
  pack_w<<<640,  256, 0, stream>>>(k0, r0, W0p, 20, 128, 100);       // layer0: K=128(pad)+512
  pack_w<<<1024, 256, 0, stream>>>(k1, r1, W1p, 32, 512, 512);       // layer1: K=512+512

  hipFuncSetAttribute(reinterpret_cast<const void*>(lstm_main),
                      hipFuncAttributeMaxDynamicSharedMemorySize, 147456);
  void* args[] = {(void*)&b0, (void*)&b1, (void*)&W0p, (void*)&W1p,
                  (void*)&X,  (void*)&H0, (void*)&H1, (void*)&bar};
  (void)hipLaunchCooperativeKernel(reinterpret_cast<void*>(lstm_main),
                                   dim3(NBLK), dim3(512), args, 147456, stream);

  dense_out<<<1, 512, 0, stream>>>(H1 + (size_t)256 * 512, wd1, bd1, wd2, bd2, out);
}